// Round 1
// baseline (2708.274 us; speedup 1.0000x reference)
//
#include <hip/hip_runtime.h>
#include <hip/hip_bf16.h>
#include <cstddef>

#define NN 50000
#define NE 1600000
#define NFEAT 512
#define NHID 512
#define NSSF 256
#define NCLASS 64
#define KTH 8193   // smallest u with count(|ssf|<=u) >= 8193  -> sorted[8192]

// ---------------- CSR build (bucket edges by dst; avoids fp32 scatter atomics) ---------
__global__ void k_hist(const int* __restrict__ dst, int* __restrict__ cnt) {
  int i = blockIdx.x * blockDim.x + threadIdx.x;
  int stride = gridDim.x * blockDim.x;
  for (; i < NE; i += stride) atomicAdd(&cnt[dst[i]], 1);
}

__global__ void k_scan(const int* __restrict__ cnt, int* __restrict__ rp) {
  __shared__ int buf[1024];
  __shared__ int carry_s;
  int tid = threadIdx.x;
  if (tid == 0) { carry_s = 0; rp[0] = 0; }
  __syncthreads();
  for (int base = 0; base < NN; base += 1024) {
    int i = base + tid;
    int x = (i < NN) ? cnt[i] : 0;
    buf[tid] = x;
    __syncthreads();
    for (int off = 1; off < 1024; off <<= 1) {
      int y = (tid >= off) ? buf[tid - off] : 0;
      __syncthreads();
      buf[tid] += y;
      __syncthreads();
    }
    if (i < NN) rp[i + 1] = carry_s + buf[tid];
    __syncthreads();
    if (tid == 0) carry_s += buf[1023];
    __syncthreads();
  }
}

__global__ void k_copy_int(const int* __restrict__ a, int* __restrict__ b, int n) {
  int i = blockIdx.x * blockDim.x + threadIdx.x;
  if (i < n) b[i] = a[i];
}

__global__ void k_scatter(const int* __restrict__ src, const int* __restrict__ dst,
                          const float* __restrict__ vals, int* __restrict__ fill,
                          int* __restrict__ src_s, float* __restrict__ val_s) {
  int i = blockIdx.x * blockDim.x + threadIdx.x;
  int stride = gridDim.x * blockDim.x;
  for (; i < NE; i += stride) {
    int p = atomicAdd(&fill[dst[i]], 1);
    src_s[p] = src[i];
    val_s[p] = vals[i];
  }
}

// ---------------- fp32 GEMM + bias: C[M,N] = A[M,K] @ B[K,N] + bias -------------------
// 128x128 block tile, BK=8, 256 threads, 8x8 per thread. A staged transposed in LDS.
__global__ __launch_bounds__(256) void k_gemm_bias(
    const float* __restrict__ A, const float* __restrict__ B,
    const float* __restrict__ bias, float* __restrict__ C,
    int M, int K, int N)
{
  __shared__ __align__(16) float As[8][132];  // +4 pad: 2-way (free) write conflicts
  __shared__ __align__(16) float Bs[8][128];
  int tid = threadIdx.x;
  int bm = blockIdx.y * 128;
  int bn = blockIdx.x * 128;
  int tx = tid & 15;
  int ty = tid >> 4;

  float acc[8][8];
#pragma unroll
  for (int i = 0; i < 8; i++)
#pragma unroll
    for (int j = 0; j < 8; j++) acc[i][j] = 0.f;

  int ar = tid >> 1;          // 0..127 row within tile
  int ak = (tid & 1) * 4;     // 0 or 4
  int kr = tid >> 5;          // 0..7
  int bc = (tid & 31) * 4;    // 0..124
  bool arow_ok = (bm + ar) < M;
  const float* Ap = A + (size_t)(bm + ar) * K + ak;
  const float* Bp = B + (size_t)kr * N + bn + bc;

  for (int k0 = 0; k0 < K; k0 += 8) {
    float4 a4 = make_float4(0.f, 0.f, 0.f, 0.f);
    if (arow_ok) a4 = *(const float4*)(Ap + k0);
    float4 b4 = *(const float4*)(Bp + (size_t)k0 * N);
    __syncthreads();
    As[ak + 0][ar] = a4.x; As[ak + 1][ar] = a4.y;
    As[ak + 2][ar] = a4.z; As[ak + 3][ar] = a4.w;
    *(float4*)&Bs[kr][bc] = b4;
    __syncthreads();
#pragma unroll
    for (int kk = 0; kk < 8; kk++) {
      float4 a0 = *(const float4*)&As[kk][ty * 8];
      float4 a1 = *(const float4*)&As[kk][ty * 8 + 4];
      float4 b0 = *(const float4*)&Bs[kk][tx * 8];
      float4 b1 = *(const float4*)&Bs[kk][tx * 8 + 4];
      float af[8] = {a0.x, a0.y, a0.z, a0.w, a1.x, a1.y, a1.z, a1.w};
      float bf[8] = {b0.x, b0.y, b0.z, b0.w, b1.x, b1.y, b1.z, b1.w};
#pragma unroll
      for (int i = 0; i < 8; i++)
#pragma unroll
        for (int j = 0; j < 8; j++) acc[i][j] += af[i] * bf[j];
    }
  }

  float bb[8];
#pragma unroll
  for (int j = 0; j < 8; j++) bb[j] = bias[bn + tx * 8 + j];
#pragma unroll
  for (int i = 0; i < 8; i++) {
    int row = bm + ty * 8 + i;
    if (row < M) {
      float4 o0 = make_float4(acc[i][0] + bb[0], acc[i][1] + bb[1],
                              acc[i][2] + bb[2], acc[i][3] + bb[3]);
      float4 o1 = make_float4(acc[i][4] + bb[4], acc[i][5] + bb[5],
                              acc[i][6] + bb[6], acc[i][7] + bb[7]);
      float* crow = C + (size_t)row * N + bn + tx * 8;
      *(float4*)crow = o0;
      *(float4*)(crow + 4) = o1;
    }
  }
}

// ---------------- CSR SPMM: H[r,:] = sum_e val[e] * X[src[e],:]  (+ optional relu) ----
__global__ void k_spmm(const int* __restrict__ rp, const int* __restrict__ srcs,
                       const float* __restrict__ vals, const float* __restrict__ X,
                       float* __restrict__ H, int F, int do_relu)
{
  int r = blockIdx.x;
  int t = threadIdx.x;           // F/4 threads
  int e0 = rp[r], e1 = rp[r + 1];
  float4 acc = make_float4(0.f, 0.f, 0.f, 0.f);
  for (int e = e0; e < e1; ++e) {
    int s = srcs[e];
    float v = vals[e];
    float4 xv = *(const float4*)(X + (size_t)s * F + t * 4);
    acc.x += v * xv.x; acc.y += v * xv.y; acc.z += v * xv.z; acc.w += v * xv.w;
  }
  if (do_relu) {
    acc.x = fmaxf(acc.x, 0.f); acc.y = fmaxf(acc.y, 0.f);
    acc.z = fmaxf(acc.z, 0.f); acc.w = fmaxf(acc.w, 0.f);
  }
  *(float4*)(H + (size_t)r * F + t * 4) = acc;
}

// ---------------- rank-select threshold: |ssf| bits are order-isomorphic to values ----
__global__ void k_threshold(const float* __restrict__ ssf, float* __restrict__ thr) {
  __shared__ int red[256];
  int tid = threadIdx.x;
  unsigned lo = 0u, hi = 0x7f800000u;
  while (lo < hi) {
    unsigned mid = lo + ((hi - lo) >> 1);
    int c = 0;
    for (int i = tid; i < NSSF * NCLASS; i += 256) {
      unsigned key = __float_as_uint(ssf[i]) & 0x7fffffffu;
      c += (key <= mid) ? 1 : 0;
    }
    red[tid] = c;
    __syncthreads();
    for (int s = 128; s > 0; s >>= 1) {
      if (tid < s) red[tid] += red[tid + s];
      __syncthreads();
    }
    int total = red[0];
    __syncthreads();
    if (total >= KTH) hi = mid; else lo = mid + 1;
  }
  if (tid == 0) thr[0] = __uint_as_float(lo);
}

__global__ void k_sparsify(const float* __restrict__ ssf, const float* __restrict__ thr,
                           float* __restrict__ outp) {
  int i = blockIdx.x * blockDim.x + threadIdx.x;
  if (i < NSSF * NCLASS) {
    float v = ssf[i];
    outp[i] = (fabsf(v) >= thr[0]) ? v : 0.f;
  }
}

__global__ void k_colstats(const float* __restrict__ ssf_sp, float* __restrict__ colsq,
                           float* __restrict__ cnorm) {
  int c = threadIdx.x;  // 64
  float s = 0.f;
  for (int k = 0; k < NSSF; k++) {
    float v = ssf_sp[k * NCLASS + c];
    s += v * v;
  }
  colsq[c] = s;
  cnorm[c] = fmaxf(sqrtf(s), 1e-6f);
}

// ---------------- fused: out = h@ssf_sp, dist, cosine, 2x log-softmax, loss ----------
// 1 wave per row (64 lanes = 64 classes). ssf_sp staged in exactly 64KB LDS.
__global__ __launch_bounds__(256) void k_final(
    const float* __restrict__ h, const float* __restrict__ ssf_sp,
    const float* __restrict__ colsq, const float* __restrict__ cn,
    float* __restrict__ outp, float* __restrict__ lossp)
{
  __shared__ float s_ssf[NSSF * NCLASS];  // 65536 bytes
  int tid = threadIdx.x;
  for (int i = tid; i < NSSF * NCLASS; i += 256) s_ssf[i] = ssf_sp[i];
  __syncthreads();
  int wave = tid >> 6, lane = tid & 63;
  int r = blockIdx.x * 4 + wave;
  if (r >= NN) return;

  float4 hv = *(const float4*)(h + (size_t)r * NSSF + lane * 4);
  float hsq = hv.x * hv.x + hv.y * hv.y + hv.z * hv.z + hv.w * hv.w;
#pragma unroll
  for (int m = 1; m < 64; m <<= 1) hsq += __shfl_xor(hsq, m);

  float acc = 0.f;
  for (int k4 = 0; k4 < 64; ++k4) {
    float hx = __shfl(hv.x, k4);
    float hy = __shfl(hv.y, k4);
    float hz = __shfl(hv.z, k4);
    float hw = __shfl(hv.w, k4);
    const float* p = &s_ssf[k4 * 4 * NCLASS + lane];
    acc += hx * p[0] + hy * p[NCLASS] + hz * p[2 * NCLASS] + hw * p[3 * NCLASS];
  }
  float o = acc;
  outp[(size_t)r * NCLASS + lane] = o;

  float sq = hsq - 2.f * o + colsq[lane];
  float d = -sqrtf(fmaxf(sq, 1e-12f));
  float hn = fmaxf(sqrtf(hsq), 1e-6f);
  float sim = o / (hn * cn[lane]);

  float m1 = d;
#pragma unroll
  for (int m = 1; m < 64; m <<= 1) m1 = fmaxf(m1, __shfl_xor(m1, m));
  float s1 = expf(d - m1);
#pragma unroll
  for (int m = 1; m < 64; m <<= 1) s1 += __shfl_xor(s1, m);
  float ls1 = d - m1 - logf(s1);

  float m2 = sim;
#pragma unroll
  for (int m = 1; m < 64; m <<= 1) m2 = fmaxf(m2, __shfl_xor(m2, m));
  float s2 = expf(sim - m2);
#pragma unroll
  for (int m = 1; m < 64; m <<= 1) s2 += __shfl_xor(s2, m);
  float ls2 = sim - m2 - logf(s2);

  lossp[(size_t)r * NCLASS + lane] = 0.5f * (ls1 + ls2);
}

__global__ void k_copy_sigma(const float* __restrict__ s, float* __restrict__ o) {
  o[0] = s[0];
}

extern "C" void kernel_launch(void* const* d_in, const int* in_sizes, int n_in,
                              void* d_out, int out_size, void* d_ws, size_t ws_size,
                              hipStream_t stream)
{
  (void)in_sizes; (void)n_in; (void)out_size; (void)ws_size;
  const float* x    = (const float*)d_in[0];
  const int*   src  = (const int*)  d_in[1];
  const int*   dst  = (const int*)  d_in[2];
  const float* vals = (const float*)d_in[3];
  const float* W1 = (const float*)d_in[4];
  const float* b1 = (const float*)d_in[5];
  const float* W2 = (const float*)d_in[6];
  const float* b2 = (const float*)d_in[7];
  const float* W3 = (const float*)d_in[8];
  const float* b3 = (const float*)d_in[9];
  const float* ssf   = (const float*)d_in[10];
  const float* sigma = (const float*)d_in[11];

  // output layout: out[50000,64] | ssf_sp[256,64] | h[50000,256] | loss[50000,64] | sigma
  float* outf   = (float*)d_out;
  float* o_out  = outf;
  float* o_ssf  = outf + (size_t)NN * NCLASS;
  float* o_h    = o_ssf + NSSF * NCLASS;
  float* o_loss = o_h + (size_t)NN * NSSF;
  float* o_sig  = o_loss + (size_t)NN * NCLASS;

  // workspace: Y[50000,512] | H[50000,512] | cnt/fill | row_ptr | src_s | val_s | misc
  float* Y = (float*)d_ws;
  float* H = Y + (size_t)NN * NHID;
  int* cnt = (int*)(H + (size_t)NN * NHID);
  int* rp  = cnt + NN;
  int* srcs = rp + 50004;          // padded for alignment
  float* vls = (float*)(srcs + NE);
  float* thr = vls + NE;
  float* csq = thr + 16;
  float* cnm = csq + 64;

  // CSR build
  hipMemsetAsync(cnt, 0, NN * sizeof(int), stream);
  k_hist<<<1024, 256, 0, stream>>>(dst, cnt);
  k_scan<<<1, 1024, 0, stream>>>(cnt, rp);
  k_copy_int<<<(NN + 255) / 256, 256, 0, stream>>>(rp, cnt, NN);  // cnt becomes fill
  k_scatter<<<1024, 256, 0, stream>>>(src, dst, vals, cnt, srcs, vls);

  // 3 GCN layers
  k_gemm_bias<<<dim3(4, 391), 256, 0, stream>>>(x, W1, b1, Y, NN, NFEAT, NHID);
  k_spmm<<<NN, 128, 0, stream>>>(rp, srcs, vls, Y, H, NHID, 1);
  k_gemm_bias<<<dim3(4, 391), 256, 0, stream>>>(H, W2, b2, Y, NN, NHID, NHID);
  k_spmm<<<NN, 128, 0, stream>>>(rp, srcs, vls, Y, H, NHID, 1);
  k_gemm_bias<<<dim3(2, 391), 256, 0, stream>>>(H, W3, b3, Y, NN, NHID, NSSF);
  k_spmm<<<NN, 64, 0, stream>>>(rp, srcs, vls, Y, o_h, NSSF, 0);

  // SSF sparsify + epilogue
  k_threshold<<<1, 256, 0, stream>>>(ssf, thr);
  k_sparsify<<<(NSSF * NCLASS + 255) / 256, 256, 0, stream>>>(ssf, thr, o_ssf);
  k_colstats<<<1, 64, 0, stream>>>(o_ssf, csq, cnm);
  k_final<<<(NN + 3) / 4, 256, 0, stream>>>(o_h, o_ssf, csq, cnm, o_out, o_loss);
  k_copy_sigma<<<1, 1, 0, stream>>>(sigma, o_sig);
}

// Round 2
// 1507.993 us; speedup vs baseline: 1.7959x; 1.7959x over previous
//
#include <hip/hip_runtime.h>
#include <hip/hip_bf16.h>
#include <cstddef>

#define NN 50000
#define NE 1600000
#define NFEAT 512
#define NHID 512
#define NSSF 256
#define NCLASS 64
#define KTH 8193   // smallest u with count(|ssf|<=u) >= 8193  -> sorted[8192]

typedef unsigned short u16;
typedef u16 u16x8 __attribute__((ext_vector_type(8)));
typedef u16 u16x4 __attribute__((ext_vector_type(4)));
typedef short bf16x8 __attribute__((ext_vector_type(8)));
typedef float f32x4 __attribute__((ext_vector_type(4)));

__device__ __forceinline__ float bf2f(u16 u) {
  union { unsigned u; float f; } c; c.u = ((unsigned)u) << 16; return c.f;
}
__device__ __forceinline__ u16 f2bf(float f) {
  __hip_bfloat16 b = __float2bfloat16(f);   // RNE
  union { __hip_bfloat16 b; u16 u; } c; c.b = b; return c.u;
}

// ---------------- CSR build (bucket edges by dst; avoids fp32 scatter atomics) --------
__global__ void k_hist(const int* __restrict__ dst, int* __restrict__ cnt) {
  int i = blockIdx.x * blockDim.x + threadIdx.x;
  int stride = gridDim.x * blockDim.x;
  for (; i < NE; i += stride) atomicAdd(&cnt[dst[i]], 1);
}

__global__ void k_scan(const int* __restrict__ cnt, int* __restrict__ rp) {
  __shared__ int buf[1024];
  __shared__ int carry_s;
  int tid = threadIdx.x;
  if (tid == 0) { carry_s = 0; rp[0] = 0; }
  __syncthreads();
  for (int base = 0; base < NN; base += 1024) {
    int i = base + tid;
    int x = (i < NN) ? cnt[i] : 0;
    buf[tid] = x;
    __syncthreads();
    for (int off = 1; off < 1024; off <<= 1) {
      int y = (tid >= off) ? buf[tid - off] : 0;
      __syncthreads();
      buf[tid] += y;
      __syncthreads();
    }
    if (i < NN) rp[i + 1] = carry_s + buf[tid];
    __syncthreads();
    if (tid == 0) carry_s += buf[1023];
    __syncthreads();
  }
}

__global__ void k_copy_int(const int* __restrict__ a, int* __restrict__ b, int n) {
  int i = blockIdx.x * blockDim.x + threadIdx.x;
  if (i < n) b[i] = a[i];
}

__global__ void k_scatter(const int* __restrict__ src, const int* __restrict__ dst,
                          const float* __restrict__ vals, int* __restrict__ fill,
                          int* __restrict__ src_s, float* __restrict__ val_s) {
  int i = blockIdx.x * blockDim.x + threadIdx.x;
  int stride = gridDim.x * blockDim.x;
  for (; i < NE; i += stride) {
    int p = atomicAdd(&fill[dst[i]], 1);
    src_s[p] = src[i];
    val_s[p] = vals[i];
  }
}

// ---------------- fp32 -> bf16 bulk convert ------------------------------------------
__global__ void k_cvt_bf16(const float* __restrict__ x, u16* __restrict__ xb, int n4) {
  int i = blockIdx.x * blockDim.x + threadIdx.x;
  if (i < n4) {
    float4 v = *(const float4*)(x + (size_t)i * 4);
    u16x4 o;
    o[0] = f2bf(v.x); o[1] = f2bf(v.y); o[2] = f2bf(v.z); o[3] = f2bf(v.w);
    *(u16x4*)(xb + (size_t)i * 4) = o;
  }
}

// ---------------- W[K][N] fp32 -> Wt[N][K] bf16 --------------------------------------
__global__ void k_wt(const float* __restrict__ W, u16* __restrict__ Wt, int K, int N) {
  int idx = blockIdx.x * blockDim.x + threadIdx.x;
  if (idx < N * K) {
    int n = idx / K, k = idx % K;
    Wt[idx] = f2bf(W[(size_t)k * N + n]);
  }
}

// ---------------- bf16 MFMA GEMM: C[M,N] = bf16(A[M,K] @ Bt[N,K]^T + bias) -----------
// 128x128 tile, BK=32, 256 threads = 4 waves (2x2), each wave 64x64 = 4x4 MFMA 16x16x32
__global__ __launch_bounds__(256, 2) void k_gemm_mfma(
    const u16* __restrict__ A, const u16* __restrict__ Bt,
    const float* __restrict__ bias, u16* __restrict__ C,
    int M, int K, int N)
{
  __shared__ __align__(16) u16 As[128 * 32];
  __shared__ __align__(16) u16 Bs[128 * 32];
  int tid = threadIdx.x;
  int bm = blockIdx.y * 128;
  int bn = blockIdx.x * 128;

  // staging: 512 chunks of 8 bf16 (16B); thread t does chunks t and t+256
  int c0 = tid, c1 = tid + 256;
  int ar0 = c0 >> 2, as0 = (c0 & 3) * 8;
  int ar1 = c1 >> 2, as1 = (c1 & 3) * 8;
  bool ok0 = (bm + ar0) < M;
  bool ok1 = (bm + ar1) < M;
  const u16* Ap0 = A + (size_t)(bm + ar0) * K + as0;
  const u16* Ap1 = A + (size_t)(bm + ar1) * K + as1;
  const u16* Bp0 = Bt + (size_t)(bn + ar0) * K + as0;
  const u16* Bp1 = Bt + (size_t)(bn + ar1) * K + as1;

  int wave = tid >> 6, lane = tid & 63;
  int wm = (wave >> 1) * 64, wn = (wave & 1) * 64;
  int m16 = lane & 15, quad = lane >> 4;

  f32x4 zz = {0.f, 0.f, 0.f, 0.f};
  f32x4 acc[4][4];
#pragma unroll
  for (int i = 0; i < 4; i++)
#pragma unroll
    for (int j = 0; j < 4; j++) acc[i][j] = zz;

  u16x8 zv = {0, 0, 0, 0, 0, 0, 0, 0};
  u16x8 a0r = ok0 ? *(const u16x8*)Ap0 : zv;
  u16x8 a1r = ok1 ? *(const u16x8*)Ap1 : zv;
  u16x8 b0r = *(const u16x8*)Bp0;
  u16x8 b1r = *(const u16x8*)Bp1;

  for (int k0 = 0; k0 < K; k0 += 32) {
    __syncthreads();
    *(u16x8*)&As[ar0 * 32 + as0] = a0r;
    *(u16x8*)&As[ar1 * 32 + as1] = a1r;
    *(u16x8*)&Bs[ar0 * 32 + as0] = b0r;
    *(u16x8*)&Bs[ar1 * 32 + as1] = b1r;
    __syncthreads();
    int kn = k0 + 32;
    if (kn < K) {   // prefetch next K-block while MFMAs run
      a0r = ok0 ? *(const u16x8*)(Ap0 + kn) : zv;
      a1r = ok1 ? *(const u16x8*)(Ap1 + kn) : zv;
      b0r = *(const u16x8*)(Bp0 + kn);
      b1r = *(const u16x8*)(Bp1 + kn);
    }
    bf16x8 af[4], bw[4];
#pragma unroll
    for (int i = 0; i < 4; i++)
      af[i] = *(const bf16x8*)&As[(wm + i * 16 + m16) * 32 + quad * 8];
#pragma unroll
    for (int j = 0; j < 4; j++)
      bw[j] = *(const bf16x8*)&Bs[(wn + j * 16 + m16) * 32 + quad * 8];
#pragma unroll
    for (int i = 0; i < 4; i++)
#pragma unroll
      for (int j = 0; j < 4; j++)
        acc[i][j] = __builtin_amdgcn_mfma_f32_16x16x32_bf16(af[i], bw[j], acc[i][j], 0, 0, 0);
  }

#pragma unroll
  for (int j = 0; j < 4; j++) {
    int col = bn + wn + j * 16 + m16;
    float bv = bias[col];
#pragma unroll
    for (int i = 0; i < 4; i++) {
      int rbase = bm + wm + i * 16 + quad * 4;
#pragma unroll
      for (int r = 0; r < 4; r++) {
        int row = rbase + r;
        if (row < M) C[(size_t)row * N + col] = f2bf(acc[i][j][r] + bv);
      }
    }
  }
}

// ---------------- CSR SPMM, bf16 in / bf16 out, F=512, relu --------------------------
__global__ __launch_bounds__(256) void k_spmm_bf(
    const int* __restrict__ rp, const int* __restrict__ srcs,
    const float* __restrict__ vls, const u16* __restrict__ Xb,
    u16* __restrict__ Hb)
{
  int wave = threadIdx.x >> 6, lane = threadIdx.x & 63;
  int r = blockIdx.x * 4 + wave;
  if (r >= NN) return;
  int e0 = rp[r], e1 = rp[r + 1];
  float acc[8];
#pragma unroll
  for (int j = 0; j < 8; j++) acc[j] = 0.f;
  const u16* Xl = Xb + lane * 8;
  for (int e = e0; e < e1; ++e) {
    int s = srcs[e];
    float v = vls[e];
    u16x8 xv = *(const u16x8*)(Xl + (size_t)s * 512);
#pragma unroll
    for (int j = 0; j < 8; j++) acc[j] += v * bf2f(xv[j]);
  }
  u16x8 o;
#pragma unroll
  for (int j = 0; j < 8; j++) o[j] = f2bf(fmaxf(acc[j], 0.f));
  *(u16x8*)(Hb + (size_t)r * 512 + lane * 8) = o;
}

// ---------------- CSR SPMM, bf16 in / fp32 out, F=256, no relu -----------------------
__global__ __launch_bounds__(256) void k_spmm_f32out(
    const int* __restrict__ rp, const int* __restrict__ srcs,
    const float* __restrict__ vls, const u16* __restrict__ Xb,
    float* __restrict__ Hf)
{
  int wave = threadIdx.x >> 6, lane = threadIdx.x & 63;
  int r = blockIdx.x * 4 + wave;
  if (r >= NN) return;
  int e0 = rp[r], e1 = rp[r + 1];
  float4 acc = make_float4(0.f, 0.f, 0.f, 0.f);
  const u16* Xl = Xb + lane * 4;
  for (int e = e0; e < e1; ++e) {
    int s = srcs[e];
    float v = vls[e];
    u16x4 xv = *(const u16x4*)(Xl + (size_t)s * 256);
    acc.x += v * bf2f(xv[0]); acc.y += v * bf2f(xv[1]);
    acc.z += v * bf2f(xv[2]); acc.w += v * bf2f(xv[3]);
  }
  *(float4*)(Hf + (size_t)r * 256 + lane * 4) = acc;
}

// ---------------- rank-select threshold (LDS-staged) ---------------------------------
__global__ void k_threshold(const float* __restrict__ ssf, float* __restrict__ thr) {
  __shared__ unsigned skey[NSSF * NCLASS];  // 64 KB of |ssf| bit patterns
  __shared__ int red[256];
  int tid = threadIdx.x;
  for (int i = tid; i < NSSF * NCLASS; i += 256)
    skey[i] = __float_as_uint(ssf[i]) & 0x7fffffffu;
  __syncthreads();
  unsigned lo = 0u, hi = 0x7f800000u;
  while (lo < hi) {
    unsigned mid = lo + ((hi - lo) >> 1);
    int c = 0;
    for (int i = tid; i < NSSF * NCLASS; i += 256)
      c += (skey[i] <= mid) ? 1 : 0;
    red[tid] = c;
    __syncthreads();
    for (int s = 128; s > 0; s >>= 1) {
      if (tid < s) red[tid] += red[tid + s];
      __syncthreads();
    }
    int total = red[0];
    __syncthreads();
    if (total >= KTH) hi = mid; else lo = mid + 1;
  }
  if (tid == 0) thr[0] = __uint_as_float(lo);
}

__global__ void k_sparsify(const float* __restrict__ ssf, const float* __restrict__ thr,
                           float* __restrict__ outp) {
  int i = blockIdx.x * blockDim.x + threadIdx.x;
  if (i < NSSF * NCLASS) {
    float v = ssf[i];
    outp[i] = (fabsf(v) >= thr[0]) ? v : 0.f;
  }
}

__global__ void k_colstats(const float* __restrict__ ssf_sp, float* __restrict__ colsq,
                           float* __restrict__ cnorm) {
  int c = threadIdx.x;  // 64
  float s = 0.f;
  for (int k = 0; k < NSSF; k++) {
    float v = ssf_sp[k * NCLASS + c];
    s += v * v;
  }
  colsq[c] = s;
  cnorm[c] = fmaxf(sqrtf(s), 1e-6f);
}

// ---------------- fused epilogue: out, dist, cosine, 2x log-softmax, loss ------------
// persistent blocks; ssf_sp staged once per block in 64KB LDS; 1 wave per row
__global__ __launch_bounds__(256) void k_final(
    const float* __restrict__ h, const float* __restrict__ ssf_sp,
    const float* __restrict__ colsq, const float* __restrict__ cn,
    float* __restrict__ outp, float* __restrict__ lossp)
{
  __shared__ float s_ssf[NSSF * NCLASS];  // 65536 bytes
  int tid = threadIdx.x;
  for (int i = tid; i < NSSF * NCLASS; i += 256) s_ssf[i] = ssf_sp[i];
  __syncthreads();
  int wave = tid >> 6, lane = tid & 63;

  for (int r = blockIdx.x * 4 + wave; r < NN; r += gridDim.x * 4) {
    float4 hv = *(const float4*)(h + (size_t)r * NSSF + lane * 4);
    float hsq = hv.x * hv.x + hv.y * hv.y + hv.z * hv.z + hv.w * hv.w;
#pragma unroll
    for (int m = 1; m < 64; m <<= 1) hsq += __shfl_xor(hsq, m);

    float acc = 0.f;
    for (int k4 = 0; k4 < 64; ++k4) {
      float hx = __shfl(hv.x, k4);
      float hy = __shfl(hv.y, k4);
      float hz = __shfl(hv.z, k4);
      float hw = __shfl(hv.w, k4);
      const float* p = &s_ssf[k4 * 4 * NCLASS + lane];
      acc += hx * p[0] + hy * p[NCLASS] + hz * p[2 * NCLASS] + hw * p[3 * NCLASS];
    }
    float o = acc;
    outp[(size_t)r * NCLASS + lane] = o;

    float sq = hsq - 2.f * o + colsq[lane];
    float d = -sqrtf(fmaxf(sq, 1e-12f));
    float hn = fmaxf(sqrtf(hsq), 1e-6f);
    float sim = o / (hn * cn[lane]);

    float m1 = d;
#pragma unroll
    for (int m = 1; m < 64; m <<= 1) m1 = fmaxf(m1, __shfl_xor(m1, m));
    float s1 = expf(d - m1);
#pragma unroll
    for (int m = 1; m < 64; m <<= 1) s1 += __shfl_xor(s1, m);
    float ls1 = d - m1 - logf(s1);

    float m2 = sim;
#pragma unroll
    for (int m = 1; m < 64; m <<= 1) m2 = fmaxf(m2, __shfl_xor(m2, m));
    float s2 = expf(sim - m2);
#pragma unroll
    for (int m = 1; m < 64; m <<= 1) s2 += __shfl_xor(s2, m);
    float ls2 = sim - m2 - logf(s2);

    lossp[(size_t)r * NCLASS + lane] = 0.5f * (ls1 + ls2);
  }
}

__global__ void k_copy_sigma(const float* __restrict__ s, float* __restrict__ o) {
  o[0] = s[0];
}

extern "C" void kernel_launch(void* const* d_in, const int* in_sizes, int n_in,
                              void* d_out, int out_size, void* d_ws, size_t ws_size,
                              hipStream_t stream)
{
  (void)in_sizes; (void)n_in; (void)out_size; (void)ws_size;
  const float* x    = (const float*)d_in[0];
  const int*   src  = (const int*)  d_in[1];
  const int*   dst  = (const int*)  d_in[2];
  const float* vals = (const float*)d_in[3];
  const float* W1 = (const float*)d_in[4];
  const float* b1 = (const float*)d_in[5];
  const float* W2 = (const float*)d_in[6];
  const float* b2 = (const float*)d_in[7];
  const float* W3 = (const float*)d_in[8];
  const float* b3 = (const float*)d_in[9];
  const float* ssf   = (const float*)d_in[10];
  const float* sigma = (const float*)d_in[11];

  // output layout: out[50000,64] | ssf_sp[256,64] | h[50000,256] | loss[50000,64] | sigma
  float* outf   = (float*)d_out;
  float* o_out  = outf;
  float* o_ssf  = outf + (size_t)NN * NCLASS;
  float* o_h    = o_ssf + NSSF * NCLASS;
  float* o_loss = o_h + (size_t)NN * NSSF;
  float* o_sig  = o_loss + (size_t)NN * NCLASS;

  // workspace layout (bf16 feature buffers + weights + CSR)
  u16* Xb  = (u16*)d_ws;                       // [NN,512] bf16
  u16* Yb  = Xb + (size_t)NN * NFEAT;          // [NN,512] bf16 (also holds [NN,256] for Y3)
  u16* Hb  = Yb + (size_t)NN * NHID;           // [NN,512] bf16
  u16* W1t = Hb + (size_t)NN * NHID;           // [512,512]
  u16* W2t = W1t + (size_t)NFEAT * NHID;       // [512,512]
  u16* W3t = W2t + (size_t)NHID * NHID;        // [256,512]
  int* cnt = (int*)(W3t + (size_t)NSSF * NHID);
  int* rp  = cnt + NN;
  int* srcs = rp + 50016;
  float* vls = (float*)(srcs + NE);
  float* thr = vls + NE;
  float* csq = thr + 16;
  float* cnm = csq + 64;

  // CSR build
  hipMemsetAsync(cnt, 0, NN * sizeof(int), stream);
  k_hist<<<1024, 256, 0, stream>>>(dst, cnt);
  k_scan<<<1, 1024, 0, stream>>>(cnt, rp);
  k_copy_int<<<(NN + 255) / 256, 256, 0, stream>>>(rp, cnt, NN);  // cnt becomes fill
  k_scatter<<<1024, 256, 0, stream>>>(src, dst, vals, cnt, srcs, vls);

  // convert x and weights to bf16 (weights transposed)
  k_cvt_bf16<<<(NN * NFEAT / 4 + 255) / 256, 256, 0, stream>>>(x, Xb, NN * NFEAT / 4);
  k_wt<<<(NFEAT * NHID + 255) / 256, 256, 0, stream>>>(W1, W1t, NFEAT, NHID);
  k_wt<<<(NHID * NHID + 255) / 256, 256, 0, stream>>>(W2, W2t, NHID, NHID);
  k_wt<<<(NHID * NSSF + 255) / 256, 256, 0, stream>>>(W3, W3t, NHID, NSSF);

  // 3 GCN layers (GEMM bf16-MFMA, SPMM bf16 gather / fp32 accum)
  k_gemm_mfma<<<dim3(4, 391), 256, 0, stream>>>(Xb, W1t, b1, Yb, NN, NFEAT, NHID);
  k_spmm_bf<<<NN / 4, 256, 0, stream>>>(rp, srcs, vls, Yb, Hb);
  k_gemm_mfma<<<dim3(4, 391), 256, 0, stream>>>(Hb, W2t, b2, Yb, NN, NHID, NHID);
  k_spmm_bf<<<NN / 4, 256, 0, stream>>>(rp, srcs, vls, Yb, Xb);   // Xb reused as H2
  k_gemm_mfma<<<dim3(2, 391), 256, 0, stream>>>(Xb, W3t, b3, Yb, NN, NHID, NSSF);
  k_spmm_f32out<<<NN / 4, 256, 0, stream>>>(rp, srcs, vls, Yb, o_h);

  // SSF sparsify + epilogue
  k_threshold<<<1, 256, 0, stream>>>(ssf, thr);
  k_sparsify<<<(NSSF * NCLASS + 255) / 256, 256, 0, stream>>>(ssf, thr, o_ssf);
  k_colstats<<<1, 64, 0, stream>>>(o_ssf, csq, cnm);
  k_final<<<512, 256, 0, stream>>>(o_h, o_ssf, csq, cnm, o_out, o_loss);
  k_copy_sigma<<<1, 1, 0, stream>>>(sigma, o_sig);
}